// Round 3
// baseline (287.424 us; speedup 1.0000x reference)
//
#include <hip/hip_runtime.h>

// MLA forward: B=2, T=2048, C=1024, LAT=256, H=16, D=64, causal, SCALE=1/8
#define SCALE 0.125f
#define SL 0.18033688011112042f  // SCALE * log2(e)

typedef __bf16 bf16x8 __attribute__((ext_vector_type(8)));
typedef short short4v __attribute__((ext_vector_type(4)));
typedef unsigned short u16x4 __attribute__((ext_vector_type(4)));
typedef float f32x4 __attribute__((ext_vector_type(4)));

__device__ __forceinline__ unsigned short f2b(float f) {
  unsigned u = __float_as_uint(f);
  u += 0x7fffu + ((u >> 16) & 1u);   // RNE; inputs here never NaN
  return (unsigned short)(u >> 16);
}

#define GLB(p) ((__attribute__((address_space(1))) void*)(void*)(p))
#define LDSP(p) ((__attribute__((address_space(3))) void*)(p))

// ---------------- cast x: fp32 -> bf16, vectorized ----------------
__global__ void cast_f32_bf16(const float* __restrict__ in, unsigned short* __restrict__ out, int n4) {
  int i = blockIdx.x * blockDim.x + threadIdx.x;
  int stride = gridDim.x * blockDim.x;
  for (; i < n4; i += stride) {
    float4 v = ((const float4*)in)[i];
    u16x4 p;
    p.x = f2b(v.x); p.y = f2b(v.y); p.z = f2b(v.z); p.w = f2b(v.w);
    ((u16x4*)out)[i] = p;
  }
}

// ---------------- transpose + cast: w[R][C] fp32 -> wT[C][R] bf16 ----------------
__global__ void transpose_cast(const float* __restrict__ w0, const float* __restrict__ w1,
                               const float* __restrict__ w2,
                               unsigned short* __restrict__ o0, unsigned short* __restrict__ o1,
                               unsigned short* __restrict__ o2, int R, int C) {
  const float* w = blockIdx.z == 0 ? w0 : (blockIdx.z == 1 ? w1 : w2);
  unsigned short* o = blockIdx.z == 0 ? o0 : (blockIdx.z == 1 ? o1 : o2);
  __shared__ float tile[32][33];
  int c0 = blockIdx.x * 32, r0 = blockIdx.y * 32;
  int tx = threadIdx.x, ty = threadIdx.y;  // 32 x 8
#pragma unroll
  for (int i = 0; i < 32; i += 8)
    tile[ty + i][tx] = w[(size_t)(r0 + ty + i) * C + c0 + tx];
  __syncthreads();
#pragma unroll
  for (int i = 0; i < 32; i += 8)
    o[(size_t)(c0 + ty + i) * R + r0 + tx] = f2b(tile[tx][ty + i]);
}

// ---------------- GEMM: C[M,N] = A[M,K] * BT[N,K]^T, bf16 MFMA ----------------
template <int MODE>
__global__ __launch_bounds__(256) void gemm_bt(
    const unsigned short* __restrict__ A0, const unsigned short* __restrict__ A1,
    const unsigned short* __restrict__ A2,
    const unsigned short* __restrict__ B0, const unsigned short* __restrict__ B1,
    const unsigned short* __restrict__ B2,
    void* __restrict__ C0, void* __restrict__ C1, void* __restrict__ C2,
    const float* __restrict__ bias, int M, int N, int K) {
  const int z = blockIdx.z;
  const unsigned short* A = z == 0 ? A0 : (z == 1 ? A1 : A2);
  const unsigned short* BT = z == 0 ? B0 : (z == 1 ? B1 : B2);
  void* C = z == 0 ? C0 : (z == 1 ? C1 : C2);

  __shared__ unsigned short lA[128 * 32];
  __shared__ unsigned short lB[128 * 32];

  const int t = threadIdx.x;
  const int n0 = blockIdx.x * 128;
  const int m0 = blockIdx.y * 128;
  const int lane = t & 63;
  const int wid = t >> 6;
  const int wr = wid >> 1, wc = wid & 1;
  const int lo = lane & 15, g = lane >> 4;

  f32x4 acc[4][4];
#pragma unroll
  for (int i = 0; i < 4; i++)
#pragma unroll
    for (int j = 0; j < 4; j++) acc[i][j] = (f32x4){0.f, 0.f, 0.f, 0.f};

  const unsigned short* ga = A + (size_t)(m0 + (t >> 2)) * K + (t & 3) * 8;
  const unsigned short* gb = BT + (size_t)(n0 + (t >> 2)) * K + (t & 3) * 8;
  const size_t rowK64 = (size_t)64 * K;

  for (int k0 = 0; k0 < K; k0 += 32) {
    __syncthreads();
    __builtin_amdgcn_global_load_lds(GLB(ga + k0), LDSP((char*)lA + t * 16), 16, 0, 0);
    __builtin_amdgcn_global_load_lds(GLB(ga + rowK64 + k0), LDSP((char*)lA + 4096 + t * 16), 16, 0, 0);
    __builtin_amdgcn_global_load_lds(GLB(gb + k0), LDSP((char*)lB + t * 16), 16, 0, 0);
    __builtin_amdgcn_global_load_lds(GLB(gb + rowK64 + k0), LDSP((char*)lB + 4096 + t * 16), 16, 0, 0);
    __syncthreads();

    bf16x8 af[4], bfr[4];
#pragma unroll
    for (int i = 0; i < 4; i++) {
      af[i] = *(const bf16x8*)&lA[(wr * 64 + i * 16 + lo) * 32 + g * 8];
      bfr[i] = *(const bf16x8*)&lB[(wc * 64 + i * 16 + lo) * 32 + g * 8];
    }
#pragma unroll
    for (int i = 0; i < 4; i++)
#pragma unroll
      for (int j = 0; j < 4; j++)
        acc[i][j] = __builtin_amdgcn_mfma_f32_16x16x32_bf16(af[i], bfr[j], acc[i][j], 0, 0, 0);
  }

  if constexpr (MODE == 2) {
    float* Cf = (float*)C;
#pragma unroll
    for (int i = 0; i < 4; i++) {
      int row0 = m0 + wr * 64 + i * 16 + g * 4;
#pragma unroll
      for (int j = 0; j < 4; j++) {
        int col = n0 + wc * 64 + j * 16 + lo;
        float bv = bias[col];
#pragma unroll
        for (int r = 0; r < 4; r++) Cf[(size_t)(row0 + r) * N + col] = acc[i][j][r] + bv;
      }
    }
  } else {
    unsigned short* Cb = (unsigned short*)C;
    if (MODE == 1 && z == 2) {
      // V^T epilogue: out[b*1024 + col][t]
#pragma unroll
      for (int i = 0; i < 4; i++) {
        int row0 = m0 + wr * 64 + i * 16 + g * 4;
        int bb = row0 >> 11, tloc = row0 & 2047;
#pragma unroll
        for (int j = 0; j < 4; j++) {
          int col = n0 + wc * 64 + j * 16 + lo;
          u16x4 pk;
#pragma unroll
          for (int r = 0; r < 4; r++) pk[r] = f2b(acc[i][j][r]);
          *(u16x4*)&Cb[((size_t)(bb * 1024) + col) * 2048 + tloc] = pk;
        }
      }
    } else {
#pragma unroll
      for (int i = 0; i < 4; i++) {
        int row0 = m0 + wr * 64 + i * 16 + g * 4;
#pragma unroll
        for (int j = 0; j < 4; j++) {
          int col = n0 + wc * 64 + j * 16 + lo;
#pragma unroll
          for (int r = 0; r < 4; r++) Cb[(size_t)(row0 + r) * N + col] = f2b(acc[i][j][r]);
        }
      }
    }
  }
}

// ---------------- flash attention, causal, swapped-QK^T, KVBLK=64, QBLK=16/wave ----------------
// S^T = mfma(K, Q): lane holds q col = lane&15, kv rows = (lane>>4)*4+r per kv-frag.
// P fragment is directly the B operand of 16x16x16 PV MFMA (k = (l>>4)*4+e).
// Grid: 1024 blocks; pair = bid&31 (fixes XCD = pair%8 -> 4 pairs/XCD, KV fits L2);
// chunk schedule balances per-CU causal work; 4 waves/block walk identical KV tiles (L1 reuse).
__global__ __launch_bounds__(256, 4) void attn_fwd(const unsigned short* __restrict__ Q,
                                                   const unsigned short* __restrict__ K,
                                                   const unsigned short* __restrict__ VT,
                                                   unsigned short* __restrict__ Y) {
  const int w = threadIdx.x >> 6;
  const int lane = threadIdx.x & 63;
  const int lo = lane & 15, g = lane >> 4;
  const int bid = blockIdx.x;
  const int pair = bid & 31;       // (b,h) -> fixed XCD
  const int code = bid >> 5;       // 0..31
  const int qq = code >> 3, kk = code & 7;
  // per-CU balanced: chunks {31-k, 16+k, 15-k, k} sum to 62 for all k
  const int chunk = qq == 0 ? 31 - kk : (qq == 1 ? 16 + kk : (qq == 2 ? 15 - kk : kk));
  const int b = pair >> 4, h = pair & 15;
  const int q0 = chunk * 64 + w * 16;  // this wave's 16 q rows

  const unsigned short* Qb = Q + (size_t)(b * 2048) * 1024 + h * 64;
  const unsigned short* Kb = K + (size_t)(b * 2048) * 1024 + h * 64;
  const unsigned short* Vb = VT + (size_t)((b * 16 + h) * 64) * 2048;

  bf16x8 qf[2];
#pragma unroll
  for (int sp = 0; sp < 2; sp++)
    qf[sp] = *(const bf16x8*)(Qb + (size_t)(q0 + lo) * 1024 + sp * 32 + g * 8);

  f32x4 acc[4];
#pragma unroll
  for (int dt = 0; dt < 4; dt++) acc[dt] = (f32x4){0.f, 0.f, 0.f, 0.f};
  float mrun = -3.0e38f, lrun = 0.f;

  const int nfull = (q0 + 1) >> 6;   // == chunk for all 4 waves
  const int k0b = nfull * 64;        // single boundary (masked) tile

  bf16x8 kf[4][2];
#pragma unroll
  for (int kvf = 0; kvf < 4; kvf++)
#pragma unroll
    for (int sp = 0; sp < 2; sp++)
      kf[kvf][sp] = *(const bf16x8*)(Kb + (size_t)(kvf * 16 + lo) * 1024 + sp * 32 + g * 8);

  short4v vf[4][4];  // [dt][kvf]

#define LOADV(k0)                                                                         \
  _Pragma("unroll") for (int dt = 0; dt < 4; dt++)                                        \
  _Pragma("unroll") for (int kvf = 0; kvf < 4; kvf++)                                     \
      vf[dt][kvf] = *(const short4v*)(Vb + (size_t)(dt * 16 + lo) * 2048 + (k0) + kvf * 16 + g * 4);

#define QK(st)                                                                            \
  __builtin_amdgcn_s_setprio(1);                                                          \
  _Pragma("unroll") for (int kvf = 0; kvf < 4; kvf++) {                                   \
    st[kvf] = __builtin_amdgcn_mfma_f32_16x16x32_bf16(kf[kvf][0], qf[0],                  \
                                                      (f32x4){0.f, 0.f, 0.f, 0.f}, 0, 0, 0); \
    st[kvf] = __builtin_amdgcn_mfma_f32_16x16x32_bf16(kf[kvf][1], qf[1], st[kvf], 0, 0, 0); \
  }                                                                                       \
  __builtin_amdgcn_s_setprio(0);

#define SOFTMAX_PV(st)                                                                    \
  {                                                                                       \
    /* tree max over 16 vals */                                                           \
    f32x4 m01, m23;                                                                       \
    _Pragma("unroll") for (int r = 0; r < 4; r++) {                                       \
      m01[r] = fmaxf(st[0][r], st[1][r]);                                                 \
      m23[r] = fmaxf(st[2][r], st[3][r]);                                                 \
    }                                                                                     \
    float t0 = fmaxf(fmaxf(m01[0], m01[1]), fmaxf(m01[2], m01[3]));                       \
    float t1 = fmaxf(fmaxf(m23[0], m23[1]), fmaxf(m23[2], m23[3]));                       \
    float tmax = fmaxf(t0, t1);                                                           \
    tmax = fmaxf(tmax, __shfl_xor(tmax, 16));                                             \
    tmax = fmaxf(tmax, __shfl_xor(tmax, 32));                                             \
    float tl = tmax * SL;                                                                 \
    if (!__all(tl <= mrun + 8.f)) {                                                       \
      float nm = fmaxf(mrun, tl);                                                         \
      float al = exp2f(mrun - nm);                                                        \
      mrun = nm;                                                                          \
      lrun *= al;                                                                         \
      _Pragma("unroll") for (int dt = 0; dt < 4; dt++) acc[dt] *= al;                     \
    }                                                                                     \
    float ps[4];                                                                          \
    u16x4 pbs[4];                                                                         \
    _Pragma("unroll") for (int kvf = 0; kvf < 4; kvf++) {                                 \
      float p0 = exp2f(__builtin_fmaf(st[kvf][0], SL, -mrun));                            \
      float p1 = exp2f(__builtin_fmaf(st[kvf][1], SL, -mrun));                            \
      float p2 = exp2f(__builtin_fmaf(st[kvf][2], SL, -mrun));                            \
      float p3 = exp2f(__builtin_fmaf(st[kvf][3], SL, -mrun));                            \
      ps[kvf] = (p0 + p1) + (p2 + p3);                                                    \
      pbs[kvf][0] = f2b(p0); pbs[kvf][1] = f2b(p1);                                       \
      pbs[kvf][2] = f2b(p2); pbs[kvf][3] = f2b(p3);                                       \
    }                                                                                     \
    lrun += (ps[0] + ps[1]) + (ps[2] + ps[3]);                                            \
    __builtin_amdgcn_s_setprio(1);                                                        \
    _Pragma("unroll") for (int dt = 0; dt < 4; dt++)                                      \
    _Pragma("unroll") for (int kvf = 0; kvf < 4; kvf++)                                   \
        acc[dt] = __builtin_amdgcn_mfma_f32_16x16x16bf16_1k(                              \
            vf[dt][kvf], (short4v)pbs[kvf], acc[dt], 0, 0, 0);                            \
    __builtin_amdgcn_s_setprio(0);                                                        \
  }

  for (int t = 0; t < nfull; ++t) {
    const int k0 = t * 64;
    LOADV(k0);
    f32x4 st[4];
    QK(st);
    // prefetch next K tile into same regs (WAR keeps order; t+1==nfull -> boundary tile)
    const int kn = k0 + 64;
#pragma unroll
    for (int kvf = 0; kvf < 4; kvf++)
#pragma unroll
      for (int sp = 0; sp < 2; sp++)
        kf[kvf][sp] = *(const bf16x8*)(Kb + (size_t)(kn + kvf * 16 + lo) * 1024 + sp * 32 + g * 8);
    SOFTMAX_PV(st);
  }

  // boundary tile (kf already holds it)
  {
    LOADV(k0b);
    f32x4 st[4];
    QK(st);
    const int qg = q0 + lo;
#pragma unroll
    for (int kvf = 0; kvf < 4; kvf++)
#pragma unroll
      for (int r = 0; r < 4; r++) {
        int tk = k0b + kvf * 16 + g * 4 + r;
        if (tk > qg) st[kvf][r] = -3.0e38f;
      }
    SOFTMAX_PV(st);
  }

  // epilogue
  {
    float l = lrun;
    l += __shfl_xor(l, 16);
    l += __shfl_xor(l, 32);
    float inv = 1.0f / l;
    unsigned short* yp = Y + (size_t)(b * 2048 + q0 + lo) * 1024 + h * 64;
#pragma unroll
    for (int dt = 0; dt < 4; dt++) {
      u16x4 pk;
#pragma unroll
      for (int r = 0; r < 4; r++) pk[r] = f2b(acc[dt][r] * inv);
      *(u16x4*)&yp[dt * 16 + g * 4] = pk;
    }
  }
#undef LOADV
#undef QK
#undef SOFTMAX_PV
}

// ---------------- launcher ----------------
extern "C" void kernel_launch(void* const* d_in, const int* in_sizes, int n_in,
                              void* d_out, int out_size, void* d_ws, size_t ws_size,
                              hipStream_t stream) {
  const float* x = (const float*)d_in[0];
  const float* wq_lat = (const float*)d_in[1];
  const float* wk_lat = (const float*)d_in[2];
  const float* wv_lat = (const float*)d_in[3];
  const float* wq_h = (const float*)d_in[4];
  const float* wk_h = (const float*)d_in[5];
  const float* wv_h = (const float*)d_in[6];
  const float* w_proj = (const float*)d_in[7];
  const float* b_proj = (const float*)d_in[8];
  float* out = (float*)d_out;

  char* ws = (char*)d_ws;
  unsigned short* x_bf = (unsigned short*)(ws + 0);          // 4096x1024
  unsigned short* wlatT = (unsigned short*)(ws + 8388608);   // 3 x [256][1024]
  unsigned short* whT = (unsigned short*)(ws + 9961472);     // 3 x [1024][256]
  unsigned short* wpT = (unsigned short*)(ws + 11534336);    // [1024][1024]
  unsigned short* lat = (unsigned short*)(ws + 13631488);    // 3 x [4096][256]
  unsigned short* q_bf = (unsigned short*)(ws + 19922944);   // [4096][1024]
  unsigned short* k_bf = (unsigned short*)(ws + 28311552);   // [4096][1024]
  unsigned short* vT = (unsigned short*)(ws + 36700160);     // [2][16][64][2048]
  unsigned short* y_bf = (unsigned short*)(ws + 45088768);   // [4096][1024]

  cast_f32_bf16<<<1024, 256, 0, stream>>>(x, x_bf, 4194304 / 4);
  transpose_cast<<<dim3(8, 32, 3), dim3(32, 8), 0, stream>>>(
      wq_lat, wk_lat, wv_lat, wlatT, wlatT + 262144, wlatT + 524288, 1024, 256);
  transpose_cast<<<dim3(32, 8, 3), dim3(32, 8), 0, stream>>>(
      wq_h, wk_h, wv_h, whT, whT + 262144, whT + 524288, 256, 1024);
  transpose_cast<<<dim3(32, 32, 1), dim3(32, 8), 0, stream>>>(
      w_proj, w_proj, w_proj, wpT, wpT, wpT, 1024, 1024);

  gemm_bt<0><<<dim3(2, 32, 3), 256, 0, stream>>>(
      x_bf, x_bf, x_bf, wlatT, wlatT + 262144, wlatT + 524288,
      lat, lat + 1048576, lat + 2097152, nullptr, 4096, 256, 1024);
  gemm_bt<1><<<dim3(8, 32, 3), 256, 0, stream>>>(
      lat, lat + 1048576, lat + 2097152, whT, whT + 262144, whT + 524288,
      q_bf, k_bf, vT, nullptr, 4096, 1024, 256);

  attn_fwd<<<1024, 256, 0, stream>>>(q_bf, k_bf, vT, y_bf);

  gemm_bt<2><<<dim3(8, 32, 1), 256, 0, stream>>>(
      y_bf, y_bf, y_bf, wpT, wpT, wpT, out, out, out, b_proj, 4096, 1024, 1024);
}

// Round 4
// 139.528 us; speedup vs baseline: 2.0600x; 2.0600x over previous
//
#include <hip/hip_runtime.h>

// MLA forward: B=2, T=2048, C=1024, LAT=256, H=16, D=64, causal, SCALE=1/8
#define SCALE 0.125f
#define SL 0.18033688011112042f  // SCALE * log2(e)

typedef __bf16 bf16x8 __attribute__((ext_vector_type(8)));
typedef short short4v __attribute__((ext_vector_type(4)));
typedef unsigned short u16x4 __attribute__((ext_vector_type(4)));
typedef float f32x4 __attribute__((ext_vector_type(4)));

__device__ __forceinline__ unsigned short f2b(float f) {
  unsigned u = __float_as_uint(f);
  u += 0x7fffu + ((u >> 16) & 1u);   // RNE; inputs here never NaN
  return (unsigned short)(u >> 16);
}

#define GLB(p) ((__attribute__((address_space(1))) void*)(void*)(p))
#define LDSP(p) ((__attribute__((address_space(3))) void*)(p))

// ---------------- cast x: fp32 -> bf16, vectorized ----------------
__global__ void cast_f32_bf16(const float* __restrict__ in, unsigned short* __restrict__ out, int n4) {
  int i = blockIdx.x * blockDim.x + threadIdx.x;
  int stride = gridDim.x * blockDim.x;
  for (; i < n4; i += stride) {
    float4 v = ((const float4*)in)[i];
    u16x4 p;
    p.x = f2b(v.x); p.y = f2b(v.y); p.z = f2b(v.z); p.w = f2b(v.w);
    ((u16x4*)out)[i] = p;
  }
}

// ---------------- transpose + cast: w[R][C] fp32 -> wT[C][R] bf16 ----------------
__global__ void transpose_cast(const float* __restrict__ w0, const float* __restrict__ w1,
                               const float* __restrict__ w2,
                               unsigned short* __restrict__ o0, unsigned short* __restrict__ o1,
                               unsigned short* __restrict__ o2, int R, int C) {
  const float* w = blockIdx.z == 0 ? w0 : (blockIdx.z == 1 ? w1 : w2);
  unsigned short* o = blockIdx.z == 0 ? o0 : (blockIdx.z == 1 ? o1 : o2);
  __shared__ float tile[32][33];
  int c0 = blockIdx.x * 32, r0 = blockIdx.y * 32;
  int tx = threadIdx.x, ty = threadIdx.y;  // 32 x 8
#pragma unroll
  for (int i = 0; i < 32; i += 8)
    tile[ty + i][tx] = w[(size_t)(r0 + ty + i) * C + c0 + tx];
  __syncthreads();
#pragma unroll
  for (int i = 0; i < 32; i += 8)
    o[(size_t)(c0 + ty + i) * R + r0 + tx] = f2b(tile[tx][ty + i]);
}

// ---------------- GEMM: C[M,N] = A[M,K] * BT[N,K]^T, bf16 MFMA ----------------
template <int MODE>
__global__ __launch_bounds__(256) void gemm_bt(
    const unsigned short* __restrict__ A0, const unsigned short* __restrict__ A1,
    const unsigned short* __restrict__ A2,
    const unsigned short* __restrict__ B0, const unsigned short* __restrict__ B1,
    const unsigned short* __restrict__ B2,
    void* __restrict__ C0, void* __restrict__ C1, void* __restrict__ C2,
    const float* __restrict__ bias, int M, int N, int K) {
  const int z = blockIdx.z;
  const unsigned short* A = z == 0 ? A0 : (z == 1 ? A1 : A2);
  const unsigned short* BT = z == 0 ? B0 : (z == 1 ? B1 : B2);
  void* C = z == 0 ? C0 : (z == 1 ? C1 : C2);

  __shared__ unsigned short lA[128 * 32];
  __shared__ unsigned short lB[128 * 32];

  const int t = threadIdx.x;
  const int n0 = blockIdx.x * 128;
  const int m0 = blockIdx.y * 128;
  const int lane = t & 63;
  const int wid = t >> 6;
  const int wr = wid >> 1, wc = wid & 1;
  const int lo = lane & 15, g = lane >> 4;

  f32x4 acc[4][4];
#pragma unroll
  for (int i = 0; i < 4; i++)
#pragma unroll
    for (int j = 0; j < 4; j++) acc[i][j] = (f32x4){0.f, 0.f, 0.f, 0.f};

  const unsigned short* ga = A + (size_t)(m0 + (t >> 2)) * K + (t & 3) * 8;
  const unsigned short* gb = BT + (size_t)(n0 + (t >> 2)) * K + (t & 3) * 8;
  const size_t rowK64 = (size_t)64 * K;

  for (int k0 = 0; k0 < K; k0 += 32) {
    __syncthreads();
    __builtin_amdgcn_global_load_lds(GLB(ga + k0), LDSP((char*)lA + t * 16), 16, 0, 0);
    __builtin_amdgcn_global_load_lds(GLB(ga + rowK64 + k0), LDSP((char*)lA + 4096 + t * 16), 16, 0, 0);
    __builtin_amdgcn_global_load_lds(GLB(gb + k0), LDSP((char*)lB + t * 16), 16, 0, 0);
    __builtin_amdgcn_global_load_lds(GLB(gb + rowK64 + k0), LDSP((char*)lB + 4096 + t * 16), 16, 0, 0);
    __syncthreads();

    bf16x8 af[4], bfr[4];
#pragma unroll
    for (int i = 0; i < 4; i++) {
      af[i] = *(const bf16x8*)&lA[(wr * 64 + i * 16 + lo) * 32 + g * 8];
      bfr[i] = *(const bf16x8*)&lB[(wc * 64 + i * 16 + lo) * 32 + g * 8];
    }
#pragma unroll
    for (int i = 0; i < 4; i++)
#pragma unroll
      for (int j = 0; j < 4; j++)
        acc[i][j] = __builtin_amdgcn_mfma_f32_16x16x32_bf16(af[i], bfr[j], acc[i][j], 0, 0, 0);
  }

  if constexpr (MODE == 2) {
    float* Cf = (float*)C;
#pragma unroll
    for (int i = 0; i < 4; i++) {
      int row0 = m0 + wr * 64 + i * 16 + g * 4;
#pragma unroll
      for (int j = 0; j < 4; j++) {
        int col = n0 + wc * 64 + j * 16 + lo;
        float bv = bias[col];
#pragma unroll
        for (int r = 0; r < 4; r++) Cf[(size_t)(row0 + r) * N + col] = acc[i][j][r] + bv;
      }
    }
  } else {
    unsigned short* Cb = (unsigned short*)C;
    if (MODE == 1 && z == 2) {
      // V^T epilogue: out[b*1024 + col][t]
#pragma unroll
      for (int i = 0; i < 4; i++) {
        int row0 = m0 + wr * 64 + i * 16 + g * 4;
        int bb = row0 >> 11, tloc = row0 & 2047;
#pragma unroll
        for (int j = 0; j < 4; j++) {
          int col = n0 + wc * 64 + j * 16 + lo;
          u16x4 pk;
#pragma unroll
          for (int r = 0; r < 4; r++) pk[r] = f2b(acc[i][j][r]);
          *(u16x4*)&Cb[((size_t)(bb * 1024) + col) * 2048 + tloc] = pk;
        }
      }
    } else {
#pragma unroll
      for (int i = 0; i < 4; i++) {
        int row0 = m0 + wr * 64 + i * 16 + g * 4;
#pragma unroll
        for (int j = 0; j < 4; j++) {
          int col = n0 + wc * 64 + j * 16 + lo;
#pragma unroll
          for (int r = 0; r < 4; r++) Cb[(size_t)(row0 + r) * N + col] = f2b(acc[i][j][r]);
        }
      }
    }
  }
}

// ---------------- flash attention, causal, swapped-QK^T, KVBLK=64, QBLK=16/wave ----------------
// Block = 4 waves covering one 64-row Q chunk of one (b,h). K/V tiles staged in LDS via
// global_load_lds (double-buffered, XOR-swizzled: lds[row][c16 ^ (row&7)] holds col c16,
// staged with inverse-swizzled global source). S^T = mfma(K,Q): lane holds q=lane&15,
// kv=(lane>>4)*4+r; P fragment feeds 16x16x16 PV MFMA B-operand directly.
__global__ __launch_bounds__(256) void attn_fwd(const unsigned short* __restrict__ Q,
                                                const unsigned short* __restrict__ K,
                                                const unsigned short* __restrict__ VT,
                                                unsigned short* __restrict__ Y) {
  __shared__ char smem[32768];  // lK[2][8KB] | lV[2][8KB]

  const int tid = threadIdx.x;
  const int w = tid >> 6;
  const int lane = tid & 63;
  const int lo = lane & 15, g = lane >> 4;
  const int lo7 = lo & 7;
  const int bid = blockIdx.x;
  const int pair = bid & 31;       // (b,h) -> fixed XCD (pair%8)
  const int code = bid >> 5;       // 0..31
  const int qq = code >> 3, kk = code & 7;
  // per-CU balanced: chunks {31-k, 16+k, 15-k, k} sum to 62 for all k
  const int chunk = qq == 0 ? 31 - kk : (qq == 1 ? 16 + kk : (qq == 2 ? 15 - kk : kk));
  const int b = pair >> 4, h = pair & 15;
  const int q0 = chunk * 64 + w * 16;  // this wave's 16 q rows

  const unsigned short* Qb = Q + (size_t)(b * 2048) * 1024 + h * 64;
  const unsigned short* Kb = K + (size_t)(b * 2048) * 1024 + h * 64;
  const unsigned short* Vb = VT + (size_t)((b * 16 + h) * 64) * 2048;

  bf16x8 qf[2];
#pragma unroll
  for (int sp = 0; sp < 2; sp++)
    qf[sp] = *(const bf16x8*)(Qb + (size_t)(q0 + lo) * 1024 + sp * 32 + g * 8);

  f32x4 acc[4];
#pragma unroll
  for (int dt = 0; dt < 4; dt++) acc[dt] = (f32x4){0.f, 0.f, 0.f, 0.f};
  float mrun = -3.0e38f, lrun = 0.f;

  const int nt = chunk + 1;  // tiles; last one is the masked boundary tile

  // stage K/V tile (64 rows x 128B each) into buffer `bi`; inverse-swizzled source
#define STAGE(tk0, bi)                                                                    \
  _Pragma("unroll") for (int is = 0; is < 2; is++) {                                      \
    int s = is * 256 + tid;                                                               \
    int row = s >> 3;                                                                     \
    int csrc = (s & 7) ^ (row & 7);                                                       \
    __builtin_amdgcn_global_load_lds(GLB(Kb + (size_t)((tk0) + row) * 1024 + csrc * 8),   \
                                     LDSP(smem + (bi)*8192 + s * 16), 16, 0, 0);          \
    __builtin_amdgcn_global_load_lds(GLB(Vb + (size_t)row * 2048 + (tk0) + csrc * 8),     \
                                     LDSP(smem + 16384 + (bi)*8192 + s * 16), 16, 0, 0);  \
  }

#define COMPUTE(k0, bi, MASKED)                                                           \
  {                                                                                       \
    const char* bk = smem + (bi)*8192;                                                    \
    const char* bv = smem + 16384 + (bi)*8192;                                            \
    bf16x8 kf[4][2];                                                                      \
    _Pragma("unroll") for (int kvf = 0; kvf < 4; kvf++)                                   \
    _Pragma("unroll") for (int sp = 0; sp < 2; sp++)                                      \
        kf[kvf][sp] = *(const bf16x8*)(bk + (kvf * 16 + lo) * 128 +                       \
                                       (((sp * 4 + g) ^ lo7) << 4));                      \
    short4v vf[4][4];                                                                     \
    _Pragma("unroll") for (int dt = 0; dt < 4; dt++)                                      \
    _Pragma("unroll") for (int kvf = 0; kvf < 4; kvf++)                                   \
        vf[dt][kvf] = *(const short4v*)(bv + (dt * 16 + lo) * 128 +                       \
                                        ((kvf * 32 + g * 8) ^ (lo7 << 4)));               \
    f32x4 st[4];                                                                          \
    __builtin_amdgcn_s_setprio(1);                                                        \
    _Pragma("unroll") for (int kvf = 0; kvf < 4; kvf++) {                                 \
      st[kvf] = __builtin_amdgcn_mfma_f32_16x16x32_bf16(kf[kvf][0], qf[0],                \
                                                        (f32x4){0.f, 0.f, 0.f, 0.f}, 0, 0, 0); \
      st[kvf] = __builtin_amdgcn_mfma_f32_16x16x32_bf16(kf[kvf][1], qf[1], st[kvf], 0, 0, 0); \
    }                                                                                     \
    __builtin_amdgcn_s_setprio(0);                                                        \
    if (MASKED) {                                                                         \
      const int qg = q0 + lo;                                                             \
      _Pragma("unroll") for (int kvf = 0; kvf < 4; kvf++)                                 \
      _Pragma("unroll") for (int r = 0; r < 4; r++) {                                     \
        int tk = (k0) + kvf * 16 + g * 4 + r;                                             \
        if (tk > qg) st[kvf][r] = -3.0e38f;                                               \
      }                                                                                   \
    }                                                                                     \
    f32x4 m01, m23;                                                                       \
    _Pragma("unroll") for (int r = 0; r < 4; r++) {                                       \
      m01[r] = fmaxf(st[0][r], st[1][r]);                                                 \
      m23[r] = fmaxf(st[2][r], st[3][r]);                                                 \
    }                                                                                     \
    float t0 = fmaxf(fmaxf(m01[0], m01[1]), fmaxf(m01[2], m01[3]));                       \
    float t1 = fmaxf(fmaxf(m23[0], m23[1]), fmaxf(m23[2], m23[3]));                       \
    float tmax = fmaxf(t0, t1);                                                           \
    tmax = fmaxf(tmax, __shfl_xor(tmax, 16));                                             \
    tmax = fmaxf(tmax, __shfl_xor(tmax, 32));                                             \
    float tl = tmax * SL;                                                                 \
    if (!__all(tl <= mrun + 8.f)) {                                                       \
      float nm = fmaxf(mrun, tl);                                                         \
      float al = exp2f(mrun - nm);                                                        \
      mrun = nm;                                                                          \
      lrun *= al;                                                                         \
      _Pragma("unroll") for (int dt = 0; dt < 4; dt++) acc[dt] *= al;                     \
    }                                                                                     \
    float ps[4];                                                                          \
    u16x4 pbs[4];                                                                         \
    _Pragma("unroll") for (int kvf = 0; kvf < 4; kvf++) {                                 \
      float p0 = exp2f(__builtin_fmaf(st[kvf][0], SL, -mrun));                            \
      float p1 = exp2f(__builtin_fmaf(st[kvf][1], SL, -mrun));                            \
      float p2 = exp2f(__builtin_fmaf(st[kvf][2], SL, -mrun));                            \
      float p3 = exp2f(__builtin_fmaf(st[kvf][3], SL, -mrun));                            \
      ps[kvf] = (p0 + p1) + (p2 + p3);                                                    \
      pbs[kvf][0] = f2b(p0); pbs[kvf][1] = f2b(p1);                                       \
      pbs[kvf][2] = f2b(p2); pbs[kvf][3] = f2b(p3);                                       \
    }                                                                                     \
    lrun += (ps[0] + ps[1]) + (ps[2] + ps[3]);                                            \
    __builtin_amdgcn_s_setprio(1);                                                        \
    _Pragma("unroll") for (int dt = 0; dt < 4; dt++)                                      \
    _Pragma("unroll") for (int kvf = 0; kvf < 4; kvf++)                                   \
        acc[dt] = __builtin_amdgcn_mfma_f32_16x16x16bf16_1k(vf[dt][kvf], (short4v)pbs[kvf], \
                                                            acc[dt], 0, 0, 0);            \
    __builtin_amdgcn_s_setprio(0);                                                        \
  }

  STAGE(0, 0);
  __syncthreads();  // emits vmcnt(0) drain + barrier
  int cur = 0;
  for (int t = 0; t < nt - 1; ++t) {
    STAGE((t + 1) * 64, cur ^ 1);   // prefetch next tile while computing current
    COMPUTE(t * 64, cur, false);
    __syncthreads();
    cur ^= 1;
  }
  COMPUTE((nt - 1) * 64, cur, true);  // boundary (masked) tile

  // epilogue
  {
    float l = lrun;
    l += __shfl_xor(l, 16);
    l += __shfl_xor(l, 32);
    float inv = 1.0f / l;
    unsigned short* yp = Y + (size_t)(b * 2048 + q0 + lo) * 1024 + h * 64;
#pragma unroll
    for (int dt = 0; dt < 4; dt++) {
      u16x4 pk;
#pragma unroll
      for (int r = 0; r < 4; r++) pk[r] = f2b(acc[dt][r] * inv);
      *(u16x4*)&yp[dt * 16 + g * 4] = pk;
    }
  }
#undef STAGE
#undef COMPUTE
}

// ---------------- launcher ----------------
extern "C" void kernel_launch(void* const* d_in, const int* in_sizes, int n_in,
                              void* d_out, int out_size, void* d_ws, size_t ws_size,
                              hipStream_t stream) {
  const float* x = (const float*)d_in[0];
  const float* wq_lat = (const float*)d_in[1];
  const float* wk_lat = (const float*)d_in[2];
  const float* wv_lat = (const float*)d_in[3];
  const float* wq_h = (const float*)d_in[4];
  const float* wk_h = (const float*)d_in[5];
  const float* wv_h = (const float*)d_in[6];
  const float* w_proj = (const float*)d_in[7];
  const float* b_proj = (const float*)d_in[8];
  float* out = (float*)d_out;

  char* ws = (char*)d_ws;
  unsigned short* x_bf = (unsigned short*)(ws + 0);          // 4096x1024
  unsigned short* wlatT = (unsigned short*)(ws + 8388608);   // 3 x [256][1024]
  unsigned short* whT = (unsigned short*)(ws + 9961472);     // 3 x [1024][256]
  unsigned short* wpT = (unsigned short*)(ws + 11534336);    // [1024][1024]
  unsigned short* lat = (unsigned short*)(ws + 13631488);    // 3 x [4096][256]
  unsigned short* q_bf = (unsigned short*)(ws + 19922944);   // [4096][1024]
  unsigned short* k_bf = (unsigned short*)(ws + 28311552);   // [4096][1024]
  unsigned short* vT = (unsigned short*)(ws + 36700160);     // [2][16][64][2048]
  unsigned short* y_bf = (unsigned short*)(ws + 45088768);   // [4096][1024]

  cast_f32_bf16<<<1024, 256, 0, stream>>>(x, x_bf, 4194304 / 4);
  transpose_cast<<<dim3(8, 32, 3), dim3(32, 8), 0, stream>>>(
      wq_lat, wk_lat, wv_lat, wlatT, wlatT + 262144, wlatT + 524288, 1024, 256);
  transpose_cast<<<dim3(32, 8, 3), dim3(32, 8), 0, stream>>>(
      wq_h, wk_h, wv_h, whT, whT + 262144, whT + 524288, 256, 1024);
  transpose_cast<<<dim3(32, 32, 1), dim3(32, 8), 0, stream>>>(
      w_proj, w_proj, w_proj, wpT, wpT, wpT, 1024, 1024);

  gemm_bt<0><<<dim3(2, 32, 3), 256, 0, stream>>>(
      x_bf, x_bf, x_bf, wlatT, wlatT + 262144, wlatT + 524288,
      lat, lat + 1048576, lat + 2097152, nullptr, 4096, 256, 1024);
  gemm_bt<1><<<dim3(8, 32, 3), 256, 0, stream>>>(
      lat, lat + 1048576, lat + 2097152, whT, whT + 262144, whT + 524288,
      q_bf, k_bf, vT, nullptr, 4096, 1024, 256);

  attn_fwd<<<1024, 256, 0, stream>>>(q_bf, k_bf, vT, y_bf);

  gemm_bt<2><<<dim3(8, 32, 1), 256, 0, stream>>>(
      y_bf, y_bf, y_bf, wpT, wpT, wpT, out, out, out, b_proj, 4096, 1024, 1024);
}